// Round 9
// baseline (379.657 us; speedup 1.0000x reference)
//
#include <hip/hip_runtime.h>
#include <math.h>

#define NB   2048
#define NS   512
#define NF   15
#define NH   32
#define NTL  24
#define BPB  4                  // batches (waves) per block
#define CHK  64                 // steps staged per chunk
#define NCHK (NS/CHK)           // 8
#define LOADS (CHK*NF/64)       // 15 per-lane loads per chunk (wave-private)

__global__ __launch_bounds__(256, 2)
void gru_fused(const float* __restrict__ x,
               const float* __restrict__ Wd,  const float* __restrict__ bd,
               const float* __restrict__ Wih, const float* __restrict__ Whh,
               const float* __restrict__ bih, const float* __restrict__ bhh,
               const float* __restrict__ Wo,  const float* __restrict__ bo,
               float* __restrict__ out)
{
    const int tid  = threadIdx.x;
    const int l    = tid & 63;          // lane within wave
    const int w    = tid >> 6;          // wave within block
    const int half = l >> 5;            // 0: j=0..15,f=0..7 | 1: j=16..31,f=8..14
    const int i    = l & 31;            // hidden index (replicated across halves)
    const int gb   = blockIdx.x * BPB + w;

    __shared__ float Wc[3*NH*NF];                 // W_ih @ W_dense (96x15)
    __shared__ float xs[2][BPB*CHK*NF + 16];      // wave-private x staging (+pad)

    // cooperative W_comb = W_ih @ W_dense
    for (int idx = tid; idx < 3*NH*NF; idx += 256) {
        const int g = idx / NF, f = idx - g*NF;
        float a = 0.f;
        #pragma unroll
        for (int k = 0; k < NH; ++k) a = fmaf(Wih[g*NH+k], Wd[k*NF+f], a);
        Wc[idx] = a;
    }

    // recurrent weights: this half's 16 j's of rows i, i+32, i+64
    const int j0 = half * 16;
    float Wr16[16], Wz16[16], Wn16[16];
    #pragma unroll
    for (int jj = 0; jj < 16; ++jj) {
        Wr16[jj] = Whh[(i       )*NH + j0 + jj];
        Wz16[jj] = Whh[(i +   NH)*NH + j0 + jj];
        Wn16[jj] = Whh[(i + 2*NH)*NH + j0 + jj];
    }
    // full biases (applied once, post cross-half combine; identical both halves)
    float br = 0.f, bz = 0.f, bnx = 0.f;
    #pragma unroll
    for (int k = 0; k < NH; ++k) {
        br  = fmaf(Wih[(i       )*NH + k], bd[k], br);
        bz  = fmaf(Wih[(i +   NH)*NH + k], bd[k], bz);
        bnx = fmaf(Wih[(i + 2*NH)*NH + k], bd[k], bnx);
    }
    br  += bih[i]        + bhh[i];
    bz  += bih[i +   NH] + bhh[i +   NH];
    bnx += bih[i + 2*NH];
    const float bnh = bhh[i + 2*NH];
    const float wo  = Wo[i];
    const float bo0 = bo[0];

    __syncthreads();   // Wc ready (only barrier in the kernel)

    // input weights: this half's f range (half1 gets f=8..14 + zero pad at f=15)
    const int f0 = half * 8;
    float Cr8[8], Cz8[8], Cn8[8];
    #pragma unroll
    for (int ff = 0; ff < 8; ++ff) {
        const int f = f0 + ff;
        const bool ok = (f < NF);
        Cr8[ff] = ok ? Wc[(i       )*NF + f] : 0.f;
        Cz8[ff] = ok ? Wc[(i +   NH)*NF + f] : 0.f;
        Cn8[ff] = ok ? Wc[(i + 2*NH)*NF + f] : 0.f;
    }

    // bpermute byte addresses: broadcast base (half0 reads lanes 0..15,
    // half1 reads lanes 48..63 which hold h[16..31]); xaddr = partner lane
    const int baddr = ((l & 32) + ((l & 32) >> 1)) * 4;
    const int xaddr = (l ^ 32) * 4;

    // wave-private staging regions
    float* myxs0 = &xs[0][w * CHK * NF];
    float* myxs1 = &xs[1][w * CHK * NF];
    const float* xb = x + (size_t)gb * NS * NF;

    float st[LOADS];
    #pragma unroll
    for (int k = 0; k < LOADS; ++k) st[k] = xb[l + k*64];
    #pragma unroll
    for (int k = 0; k < LOADS; ++k) myxs0[l + k*64] = st[k];

    float h = 0.f;
    for (int c = 0; c < NCHK; ++c) {
        float* cur = (c & 1) ? myxs1 : myxs0;
        float* nxt = (c & 1) ? myxs0 : myxs1;
        if (c + 1 < NCHK) {
            #pragma unroll
            for (int k = 0; k < LOADS; ++k)
                st[k] = xb[(c+1)*CHK*NF + l + k*64];
        }
        #pragma unroll 2
        for (int s = 0; s < CHK; ++s) {
            // x values for my f range (ff=7 in half1 reads pad, C=0 kills it)
            float xv[8];
            #pragma unroll
            for (int ff = 0; ff < 8; ++ff) xv[ff] = cur[s*NF + f0 + ff];

            // broadcast this half's 16 h values (addresses loop-invariant)
            const int hi_ = __float_as_int(h);
            float hb[16];
            #pragma unroll
            for (int jj = 0; jj < 16; ++jj)
                hb[jj] = __int_as_float(
                    __builtin_amdgcn_ds_bpermute(baddr + 4*jj, hi_));

            // recurrent partials (2 accumulators per gate to halve dep chain)
            float dr0=0.f, dr1=0.f, dz0=0.f, dz1=0.f, dn0=0.f, dn1=0.f;
            #pragma unroll
            for (int jj = 0; jj < 16; jj += 2) {
                dr0 = fmaf(Wr16[jj],   hb[jj],   dr0);
                dr1 = fmaf(Wr16[jj+1], hb[jj+1], dr1);
                dz0 = fmaf(Wz16[jj],   hb[jj],   dz0);
                dz1 = fmaf(Wz16[jj+1], hb[jj+1], dz1);
                dn0 = fmaf(Wn16[jj],   hb[jj],   dn0);
                dn1 = fmaf(Wn16[jj+1], hb[jj+1], dn1);
            }
            // input partials
            float gr = 0.f, gz = 0.f, gn = 0.f;
            #pragma unroll
            for (int ff = 0; ff < 8; ++ff) {
                gr = fmaf(Cr8[ff], xv[ff], gr);
                gz = fmaf(Cz8[ff], xv[ff], gz);
                gn = fmaf(Cn8[ff], xv[ff], gn);
            }
            float sr = dr0 + dr1 + gr;   // r: recurrent+input combine together
            float sz = dz0 + dz1 + gz;
            float dn = dn0 + dn1;        // n: recurrent stays separate (r gates it)
            // cross-half combine: partner's partial via bpermute
            sr += __int_as_float(__builtin_amdgcn_ds_bpermute(xaddr, __float_as_int(sr)));
            sz += __int_as_float(__builtin_amdgcn_ds_bpermute(xaddr, __float_as_int(sz)));
            dn += __int_as_float(__builtin_amdgcn_ds_bpermute(xaddr, __float_as_int(dn)));
            gn += __int_as_float(__builtin_amdgcn_ds_bpermute(xaddr, __float_as_int(gn)));

            const float ar = sr + br;
            const float az = sz + bz;
            const float r  = __builtin_amdgcn_rcpf(1.f + __expf(-ar));
            const float z  = __builtin_amdgcn_rcpf(1.f + __expf(-az));
            const float tt = (gn + bnx) + r*(dn + bnh);
            const float e  = __expf(-2.f*fabsf(tt));
            float th = (1.f - e) * __builtin_amdgcn_rcpf(1.f + e);
            th = copysignf(th, tt);
            h = z*(h - th) + th;         // (1-z)*tanh + z*h

            const int sg = c*CHK + s;
            if (sg >= NS - NTL) {
                // both halves identical: reduce within 32-lane half via swizzle
                float p = wo * h;
                p += __int_as_float(__builtin_amdgcn_ds_swizzle(__float_as_int(p), 0x041F));
                p += __int_as_float(__builtin_amdgcn_ds_swizzle(__float_as_int(p), 0x081F));
                p += __int_as_float(__builtin_amdgcn_ds_swizzle(__float_as_int(p), 0x101F));
                p += __int_as_float(__builtin_amdgcn_ds_swizzle(__float_as_int(p), 0x201F));
                p += __int_as_float(__builtin_amdgcn_ds_swizzle(__float_as_int(p), 0x401F));
                if (l == 0) out[gb*NTL + sg - (NS - NTL)] = p + bo0;
            }
        }
        if (c + 1 < NCHK) {
            // wave-private buffer: in-wave lgkmcnt ordering suffices, no barrier
            #pragma unroll
            for (int k = 0; k < LOADS; ++k) nxt[l + k*64] = st[k];
        }
    }
}

extern "C" void kernel_launch(void* const* d_in, const int* in_sizes, int n_in,
                              void* d_out, int out_size, void* d_ws, size_t ws_size,
                              hipStream_t stream) {
    const float* x   = (const float*)d_in[0];
    const float* Wd  = (const float*)d_in[1];
    const float* bd  = (const float*)d_in[2];
    const float* Wih = (const float*)d_in[3];
    const float* Whh = (const float*)d_in[4];
    const float* bih = (const float*)d_in[5];
    const float* bhh = (const float*)d_in[6];
    const float* Wo  = (const float*)d_in[7];
    const float* bo  = (const float*)d_in[8];
    float* out = (float*)d_out;

    dim3 grid(NB / BPB), block(256);
    hipLaunchKernelGGL(gru_fused, grid, block, 0, stream,
                       x, Wd, bd, Wih, Whh, bih, bhh, Wo, bo, out);
}